// Round 3
// baseline (2488.090 us; speedup 1.0000x reference)
//
#include <hip/hip_runtime.h>

// Problem constants
#define T_TOK 2048   // B*S
#define DIM   2048
#define NQ    16
#define NKV   4
#define HDIM  128
#define NE    32
#define TOPK  4
#define FF    1024
#define FSH   2048
#define SEQ   1024
#define MAXROWS 12288
#define MAXTILES 96

typedef __attribute__((ext_vector_type(4))) float f32x4;
typedef __attribute__((ext_vector_type(8))) short bf16x8;

__device__ __forceinline__ short f2bf(float f) {
    union { float f; unsigned u; } c; c.f = f;
    unsigned r = (c.u + 0x7fffu + ((c.u >> 16) & 1u)) >> 16;
    return (short)r;
}
__device__ __forceinline__ float bf2f(short h) {
    union { unsigned u; float f; } c; c.u = ((unsigned)(unsigned short)h) << 16;
    return c.f;
}
__device__ __forceinline__ void splitf(float v, short& hi, short& lo) {
    hi = f2bf(v);
    lo = f2bf(v - bf2f(hi));
}
// bijective XCD-chunk swizzle (m204): consecutive virtual ids land on same XCD
__device__ __forceinline__ int xcd_swz(int lin, int total) {
    int q8 = total >> 3, r8 = total & 7;
    int xcd = lin & 7, idx = lin >> 3;
    return (xcd < r8 ? xcd * (q8 + 1) : r8 * (q8 + 1) + (xcd - r8) * q8) + idx;
}

// ---------------- RMSNorm (one block per token, D=2048) ----------------
template<bool WBF, bool WF>
__global__ __launch_bounds__(256)
void rmsnorm_k(const float* __restrict__ x, const float* __restrict__ sc,
               short* __restrict__ ybf, float* __restrict__ yf)
{
    long base = (long)blockIdx.x * DIM;
    int tid = threadIdx.x;
    const float* xp = x + base + tid * 8;
    float4 a = *(const float4*)xp;
    float4 b = *(const float4*)(xp + 4);
    float ss = a.x*a.x + a.y*a.y + a.z*a.z + a.w*a.w
             + b.x*b.x + b.y*b.y + b.z*b.z + b.w*b.w;
#pragma unroll
    for (int off = 32; off > 0; off >>= 1) ss += __shfl_xor(ss, off);
    __shared__ float red[4];
    if ((tid & 63) == 0) red[tid >> 6] = ss;
    __syncthreads();
    float s = red[0] + red[1] + red[2] + red[3];
    float inv = rsqrtf(s * (1.f / DIM) + 1e-6f);
    const float* sp = sc + tid * 8;
    float4 s0 = *(const float4*)sp;
    float4 s1 = *(const float4*)(sp + 4);
    float o[8];
    o[0]=a.x*inv*s0.x; o[1]=a.y*inv*s0.y; o[2]=a.z*inv*s0.z; o[3]=a.w*inv*s0.w;
    o[4]=b.x*inv*s1.x; o[5]=b.y*inv*s1.y; o[6]=b.z*inv*s1.z; o[7]=b.w*inv*s1.w;
    if (WBF) {
        union { short s[8]; int4 v; } pk;
#pragma unroll
        for (int i = 0; i < 8; ++i) pk.s[i] = f2bf(o[i]);
        *(int4*)(ybf + base + tid * 8) = pk.v;
    }
    if (WF) {
        float4 w0; w0.x=o[0]; w0.y=o[1]; w0.z=o[2]; w0.w=o[3];
        float4 w1; w1.x=o[4]; w1.y=o[5]; w1.z=o[6]; w1.w=o[7];
        *(float4*)(yf + base + tid * 8) = w0;
        *(float4*)(yf + base + tid * 8 + 4) = w1;
    }
}

// ------- Split-precision GEMM: C[M,N] = A_f32[M,K] @ B_f32[K,N] (~fp32 acc) -------
// 3-term bf16 split: x = hi + lo; x*y ~= hi*hi + hi*lo + lo*hi  (rel err ~1e-5)
// EPI 0: Cf = acc ; 1: Cf = acc + addb
// Pipelined: K-step t+1 global loads issued before MFMA(t) (T14).
template<int EPI>
__global__ __launch_bounds__(256, 3)
void gemmsp_k(const float* __restrict__ A, const float* __restrict__ B,
              float* __restrict__ Cf, const float* __restrict__ addb,
              int N, int K)
{
    int nby = gridDim.y;
    int total = gridDim.x * nby;
    int lin = blockIdx.x + gridDim.x * blockIdx.y;
    int vt = xcd_swz(lin, total);
    int row0 = (vt / nby) * 128, col0 = (vt % nby) * 128;
    __shared__ short Ah[5120], Al[5120], Bh[5120], Bl[5120];
    int tid = threadIdx.x;
    int w = tid >> 6, l = tid & 63, g = l >> 4, lr = l & 15;
    int wr = w >> 1, wc = w & 1;
    f32x4 acc[4][4];
#pragma unroll
    for (int m = 0; m < 4; ++m)
#pragma unroll
        for (int n = 0; n < 4; ++n) acc[m][n] = (f32x4){0,0,0,0};
    int ar = tid >> 1, ak = (tid & 1) * 16;
    int bk0 = (tid >> 5) * 4, bc0 = (tid & 31) * 4;
    const float* apb = A + (long)(row0 + ar) * K + ak;
    const float* bpb = B + (long)bk0 * N + col0 + bc0;
    float4 av[4], bv[4];
#pragma unroll
    for (int q = 0; q < 4; ++q) av[q] = *(const float4*)(apb + q * 4);
#pragma unroll
    for (int q = 0; q < 4; ++q) bv[q] = *(const float4*)(bpb + (long)q * N);
    for (int kk = 0; kk < K; kk += 32) {
        __syncthreads();
        // stage A hi/lo from regs
#pragma unroll
        for (int q = 0; q < 4; ++q) {
            short4 h4, l4;
            splitf(av[q].x, h4.x, l4.x); splitf(av[q].y, h4.y, l4.y);
            splitf(av[q].z, h4.z, l4.z); splitf(av[q].w, h4.w, l4.w);
            *(short4*)(Ah + ar * 40 + ak + q * 4) = h4;
            *(short4*)(Al + ar * 40 + ak + q * 4) = l4;
        }
        // stage B hi/lo transposed 4x4, swizzled 16B blocks
#pragma unroll
        for (int j = 0; j < 4; ++j) {
            short4 h4, l4;
            splitf(((const float*)&bv[0])[j], h4.x, l4.x);
            splitf(((const float*)&bv[1])[j], h4.y, l4.y);
            splitf(((const float*)&bv[2])[j], h4.z, l4.z);
            splitf(((const float*)&bv[3])[j], h4.w, l4.w);
            int c = bc0 + j;
            int blk = (bk0 >> 3) ^ ((c >> 2) & 3);
            *(short4*)(Bh + c * 40 + blk * 8 + (bk0 & 4)) = h4;
            *(short4*)(Bl + c * 40 + blk * 8 + (bk0 & 4)) = l4;
        }
        // prefetch next K-step (in flight across barrier + ds_read + MFMA)
        if (kk + 32 < K) {
            const float* ap = apb + kk + 32;
            const float* bp = bpb + (long)(kk + 32) * N;
#pragma unroll
            for (int q = 0; q < 4; ++q) av[q] = *(const float4*)(ap + q * 4);
#pragma unroll
            for (int q = 0; q < 4; ++q) bv[q] = *(const float4*)(bp + (long)q * N);
        }
        __syncthreads();
        bf16x8 ah[4], al[4], bh[4], bl[4];
#pragma unroll
        for (int m = 0; m < 4; ++m) {
            int off = (wr * 64 + m * 16 + lr) * 40 + g * 8;
            ah[m] = *(const bf16x8*)(Ah + off);
            al[m] = *(const bf16x8*)(Al + off);
        }
#pragma unroll
        for (int n = 0; n < 4; ++n) {
            int c = wc * 64 + n * 16 + lr;
            int blk = g ^ ((c >> 2) & 3);
            bh[n] = *(const bf16x8*)(Bh + c * 40 + blk * 8);
            bl[n] = *(const bf16x8*)(Bl + c * 40 + blk * 8);
        }
#pragma unroll
        for (int m = 0; m < 4; ++m)
#pragma unroll
            for (int n = 0; n < 4; ++n) {
                acc[m][n] = __builtin_amdgcn_mfma_f32_16x16x32_bf16(al[m], bh[n], acc[m][n], 0, 0, 0);
                acc[m][n] = __builtin_amdgcn_mfma_f32_16x16x32_bf16(ah[m], bl[n], acc[m][n], 0, 0, 0);
                acc[m][n] = __builtin_amdgcn_mfma_f32_16x16x32_bf16(ah[m], bh[n], acc[m][n], 0, 0, 0);
            }
    }
#pragma unroll
    for (int m = 0; m < 4; ++m)
#pragma unroll
        for (int n = 0; n < 4; ++n)
#pragma unroll
            for (int j = 0; j < 4; ++j) {
                int row = row0 + wr * 64 + m * 16 + 4 * g + j;
                int col = col0 + wc * 64 + n * 16 + lr;
                float v = acc[m][n][j];
                if (EPI == 0) Cf[(long)row * N + col] = v;
                else Cf[(long)row * N + col] = v + addb[(long)row * N + col];
            }
}

// ---------------- bf16 GEMM (post-router path), pipelined ----------------
// EPI 2: Cbf = bf16(silu(acc0)*acc1) (DUAL) ; 4: atomicAdd(Cf[tok*DIM+col], wslot[row]*acc)
// EPI 1: Cf = acc + addb
template<int EPI, bool GATHER, bool EXPERT, bool DUAL>
__global__ __launch_bounds__(256, 3)
void gemm_k(const short* __restrict__ A, const float* __restrict__ B0g,
            const float* __restrict__ B1g, float* __restrict__ Cf,
            short* __restrict__ Cbf, const float* __restrict__ addb,
            int N, int K,
            const int* __restrict__ rowmap, const int* __restrict__ tile_e,
            const int* __restrict__ tile_base, const int* __restrict__ ntiles,
            long strideB, const float* __restrict__ wslot)
{
    int nby = gridDim.y;
    int total = gridDim.x * nby;
    int lin = blockIdx.x + gridDim.x * blockIdx.y;
    int vt = xcd_swz(lin, total);
    int bx = vt / nby, by = vt % nby;
    int row0;
    const float* B0; const float* B1 = nullptr;
    if (EXPERT) {
        if (bx >= *ntiles) return;
        int e = tile_e[bx];
        row0 = tile_base[bx];
        B0 = B0g + (long)e * strideB;
        if (DUAL) B1 = B1g + (long)e * strideB;
    } else {
        row0 = bx * 128; B0 = B0g; B1 = B1g;
    }
    int col0 = by * 128;
    extern __shared__ short lds[];
    short* As  = lds;          // [128][40]
    short* Bs0 = lds + 5120;   // [128 cols][40 k] swizzled
    short* Bs1 = lds + 10240;
    int tid = threadIdx.x;
    int w = tid >> 6, l = tid & 63, g = l >> 4, lr = l & 15;
    int wr = w >> 1, wc = w & 1;
    f32x4 acc0[4][4]; f32x4 acc1[4][4];
#pragma unroll
    for (int m = 0; m < 4; ++m)
#pragma unroll
        for (int n = 0; n < 4; ++n) {
            acc0[m][n] = (f32x4){0,0,0,0};
            if (DUAL) acc1[m][n] = (f32x4){0,0,0,0};
        }
    int ar = tid >> 2, ak = (tid & 3) * 8;
    int bk0 = (tid >> 5) * 4, bc0 = (tid & 31) * 4;
    // hoist row gather out of K-loop
    bool rok[2]; const short* abase[2];
#pragma unroll
    for (int it = 0; it < 2; ++it) {
        int r = row0 + ar + it * 64;
        int sr = GATHER ? rowmap[r] : r;
        rok[it] = (!GATHER) || (sr >= 0);
        abase[it] = A + (long)(rok[it] ? sr : 0) * K + ak;
    }
    const float* b0b = B0 + (long)bk0 * N + col0 + bc0;
    const float* b1b = DUAL ? (B1 + (long)bk0 * N + col0 + bc0) : nullptr;
    int4 aval[2]; float4 b0v[4], b1v[4];
#pragma unroll
    for (int it = 0; it < 2; ++it)
        aval[it] = rok[it] ? *(const int4*)(abase[it]) : (int4){0,0,0,0};
#pragma unroll
    for (int q = 0; q < 4; ++q) {
        b0v[q] = *(const float4*)(b0b + (long)q * N);
        if (DUAL) b1v[q] = *(const float4*)(b1b + (long)q * N);
    }
    for (int kk = 0; kk < K; kk += 32) {
        __syncthreads();
#pragma unroll
        for (int it = 0; it < 2; ++it)
            *(int4*)(As + (ar + it * 64) * 40 + ak) = aval[it];
#pragma unroll
        for (int j = 0; j < 4; ++j) {
            short4 pk;
            pk.x = f2bf(((const float*)&b0v[0])[j]);
            pk.y = f2bf(((const float*)&b0v[1])[j]);
            pk.z = f2bf(((const float*)&b0v[2])[j]);
            pk.w = f2bf(((const float*)&b0v[3])[j]);
            int c = bc0 + j;
            int blk = (bk0 >> 3) ^ ((c >> 2) & 3);
            *(short4*)(Bs0 + c * 40 + blk * 8 + (bk0 & 4)) = pk;
            if (DUAL) {
                short4 qk;
                qk.x = f2bf(((const float*)&b1v[0])[j]);
                qk.y = f2bf(((const float*)&b1v[1])[j]);
                qk.z = f2bf(((const float*)&b1v[2])[j]);
                qk.w = f2bf(((const float*)&b1v[3])[j]);
                *(short4*)(Bs1 + c * 40 + blk * 8 + (bk0 & 4)) = qk;
            }
        }
        // prefetch next K-step
        if (kk + 32 < K) {
            int ko = kk + 32;
#pragma unroll
            for (int it = 0; it < 2; ++it)
                aval[it] = rok[it] ? *(const int4*)(abase[it] + ko) : (int4){0,0,0,0};
#pragma unroll
            for (int q = 0; q < 4; ++q) {
                b0v[q] = *(const float4*)(b0b + (long)(ko + q) * N);
                if (DUAL) b1v[q] = *(const float4*)(b1b + (long)(ko + q) * N);
            }
        }
        __syncthreads();
        bf16x8 af[4], b0f[4], b1f[4];
#pragma unroll
        for (int m = 0; m < 4; ++m)
            af[m] = *(const bf16x8*)(As + (wr * 64 + m * 16 + lr) * 40 + g * 8);
#pragma unroll
        for (int n = 0; n < 4; ++n) {
            int c = wc * 64 + n * 16 + lr;
            int blk = g ^ ((c >> 2) & 3);
            b0f[n] = *(const bf16x8*)(Bs0 + c * 40 + blk * 8);
            if (DUAL) b1f[n] = *(const bf16x8*)(Bs1 + c * 40 + blk * 8);
        }
#pragma unroll
        for (int m = 0; m < 4; ++m)
#pragma unroll
            for (int n = 0; n < 4; ++n) {
                acc0[m][n] = __builtin_amdgcn_mfma_f32_16x16x32_bf16(af[m], b0f[n], acc0[m][n], 0, 0, 0);
                if (DUAL)
                    acc1[m][n] = __builtin_amdgcn_mfma_f32_16x16x32_bf16(af[m], b1f[n], acc1[m][n], 0, 0, 0);
            }
    }
#pragma unroll
    for (int m = 0; m < 4; ++m)
#pragma unroll
        for (int n = 0; n < 4; ++n)
#pragma unroll
            for (int j = 0; j < 4; ++j) {
                int row = row0 + wr * 64 + m * 16 + 4 * g + j;
                int col = col0 + wc * 64 + n * 16 + lr;
                float v = acc0[m][n][j];
                if (EPI == 1) Cf[(long)row * N + col] = v + addb[(long)row * N + col];
                else if (EPI == 2) {
                    float uu = acc1[m][n][j];
                    float sg = v / (1.f + __expf(-v));
                    Cbf[(long)row * N + col] = f2bf(sg * uu);
                } else if (EPI == 4) {
                    int tok = rowmap[row];
                    if (tok >= 0) atomicAdd(&Cf[(long)tok * DIM + col], wslot[row] * v);
                }
            }
}

// ---------------- qk-norm + neox RoPE + scale, fp32 in-place ----------------
__global__ __launch_bounds__(256)
void rope_k(float* __restrict__ qf, float* __restrict__ kf,
            const float* __restrict__ qn, const float* __restrict__ kn,
            const int* __restrict__ posp)
{
    int t = blockIdx.x;
    int w = threadIdx.x >> 6, l = threadIdx.x & 63;
    int hi = blockIdx.y * 4 + w;   // 0..19
    float* src; const float* nrm; float esc;
    if (hi < NQ) {
        src = qf + (long)t * DIM + hi * HDIM; nrm = qn;
        esc = 0.08838834764831843f;  // HD^-0.5 folded into q
    } else {
        int kh = hi - NQ;
        src = kf + (long)t * (NKV * HDIM) + kh * HDIM; nrm = kn;
        esc = 1.f;
    }
    float x1 = src[l], x2 = src[l + 64];
    float ss = x1 * x1 + x2 * x2;
#pragma unroll
    for (int off = 32; off > 0; off >>= 1) ss += __shfl_xor(ss, off);
    float inv = rsqrtf(ss * (1.f / HDIM) + 1e-6f);
    float a1 = x1 * inv * nrm[l], a2 = x2 * inv * nrm[l + 64];
    float p = (float)posp[t];
    float fr = expf((float)l * -0.21586735246819178f); // -ln(1e6)/64
    float ang = p * fr;
    float cv = cosf(ang), sv = sinf(ang);
    src[l]      = (a1 * cv - a2 * sv) * esc;
    src[l + 64] = (a1 * sv + a2 * cv) * esc;
}

// ---------------- flash attention (causal, GQA) — split-bf16, ~fp32 ----------------
__global__ __launch_bounds__(256)
void attn_k(const float* __restrict__ qf, const float* __restrict__ kf,
            const float* __restrict__ vf, float* __restrict__ of)
{
    int blk = blockIdx.x;
    int qt = blk & 15, bh = blk >> 4;
    int h = bh & (NQ - 1), b = bh >> 4;
    int kvh = h >> 2;
    int tid = threadIdx.x;
    int w = tid >> 6, l = tid & 63, g = l >> 4, lr = l & 15;
    int q0 = qt * 64, qbase = q0 + w * 16;
    const float* qp = qf + ((long)(b * SEQ + qbase + lr) * DIM + h * HDIM);
    bf16x8 qh[4], ql[4];
#pragma unroll
    for (int kc = 0; kc < 4; ++kc) {
        float4 f0 = *(const float4*)(qp + kc * 32 + 8 * g);
        float4 f1 = *(const float4*)(qp + kc * 32 + 8 * g + 4);
        union { short s[8]; bf16x8 v; } uh, ul;
#pragma unroll
        for (int i = 0; i < 4; ++i) {
            splitf(((const float*)&f0)[i], uh.s[i], ul.s[i]);
            splitf(((const float*)&f1)[i], uh.s[4 + i], ul.s[4 + i]);
        }
        qh[kc] = uh.v; ql[kc] = ul.v;
    }
    f32x4 o[8];
#pragma unroll
    for (int i = 0; i < 8; ++i) o[i] = (f32x4){0,0,0,0};
    float mr[4] = {-1e30f, -1e30f, -1e30f, -1e30f};
    float ls[4] = {0, 0, 0, 0};
    __shared__ short Vth[5120], Vtl[5120];      // [hd][40 keys]
    __shared__ short Plh[2560], Pll[2560];      // per-wave [16 q][40 keys]
    int nsteps = 2 * (qt + 1);
    for (int st = 0; st < nsteps; ++st) {
        int kb = st * 32;
        __syncthreads();
        {   // stage V transposed + split: Vt[hd][key]
            int key = tid >> 3, hx = (tid & 7) * 16;
            const float* vp = vf + ((long)(b * SEQ + kb + key) * (NKV * HDIM) + kvh * HDIM + hx);
#pragma unroll
            for (int q = 0; q < 4; ++q) {
                float4 v = *(const float4*)(vp + q * 4);
#pragma unroll
                for (int i = 0; i < 4; ++i) {
                    short hh, ll;
                    splitf(((const float*)&v)[i], hh, ll);
                    Vth[(hx + q * 4 + i) * 40 + key] = hh;
                    Vtl[(hx + q * 4 + i) * 40 + key] = ll;
                }
            }
        }
        __syncthreads();
        f32x4 sa[2]; sa[0] = (f32x4){0,0,0,0}; sa[1] = (f32x4){0,0,0,0};
#pragma unroll
        for (int kc = 0; kc < 4; ++kc)
#pragma unroll
            for (int n = 0; n < 2; ++n) {
                const float* kp = kf + ((long)(b * SEQ + kb + n * 16 + lr) * (NKV * HDIM) + kvh * HDIM + kc * 32 + 8 * g);
                float4 f0 = *(const float4*)kp;
                float4 f1 = *(const float4*)(kp + 4);
                union { short s[8]; bf16x8 v; } uh, ul;
#pragma unroll
                for (int i = 0; i < 4; ++i) {
                    splitf(((const float*)&f0)[i], uh.s[i], ul.s[i]);
                    splitf(((const float*)&f1)[i], uh.s[4 + i], ul.s[4 + i]);
                }
                sa[n] = __builtin_amdgcn_mfma_f32_16x16x32_bf16(ql[kc], uh.v, sa[n], 0, 0, 0);
                sa[n] = __builtin_amdgcn_mfma_f32_16x16x32_bf16(qh[kc], ul.v, sa[n], 0, 0, 0);
                sa[n] = __builtin_amdgcn_mfma_f32_16x16x32_bf16(qh[kc], uh.v, sa[n], 0, 0, 0);
            }
        // causal mask
#pragma unroll
        for (int n = 0; n < 2; ++n)
#pragma unroll
            for (int j = 0; j < 4; ++j) {
                int key = kb + n * 16 + lr;
                int qr = qbase + 4 * g + j;
                if (key > qr) sa[n][j] = -1e30f;
            }
        // online softmax (fp32), P stored as hi/lo bf16 planes
#pragma unroll
        for (int j = 0; j < 4; ++j) {
            float v = fmaxf(sa[0][j], sa[1][j]);
#pragma unroll
            for (int off = 1; off < 16; off <<= 1) v = fmaxf(v, __shfl_xor(v, off));
            float mn = fmaxf(mr[j], v);
            float sc = __expf(mr[j] - mn);
            mr[j] = mn;
            float p0 = __expf(sa[0][j] - mn);
            float p1 = __expf(sa[1][j] - mn);
            float rs = p0 + p1;
#pragma unroll
            for (int off = 1; off < 16; off <<= 1) rs += __shfl_xor(rs, off);
            ls[j] = ls[j] * sc + rs;
            short hh, ll;
            splitf(p0, hh, ll);
            Plh[w * 640 + (4 * g + j) * 40 + lr] = hh;
            Pll[w * 640 + (4 * g + j) * 40 + lr] = ll;
            splitf(p1, hh, ll);
            Plh[w * 640 + (4 * g + j) * 40 + 16 + lr] = hh;
            Pll[w * 640 + (4 * g + j) * 40 + 16 + lr] = ll;
#pragma unroll
            for (int nf = 0; nf < 8; ++nf) o[nf][j] *= sc;
        }
        asm volatile("s_waitcnt lgkmcnt(0)" ::: "memory");
        bf16x8 pah = *(const bf16x8*)(Plh + w * 640 + lr * 40 + 8 * g);
        bf16x8 pal = *(const bf16x8*)(Pll + w * 640 + lr * 40 + 8 * g);
#pragma unroll
        for (int nf = 0; nf < 8; ++nf) {
            bf16x8 vh = *(const bf16x8*)(Vth + (nf * 16 + lr) * 40 + 8 * g);
            bf16x8 vl = *(const bf16x8*)(Vtl + (nf * 16 + lr) * 40 + 8 * g);
            o[nf] = __builtin_amdgcn_mfma_f32_16x16x32_bf16(pal, vh, o[nf], 0, 0, 0);
            o[nf] = __builtin_amdgcn_mfma_f32_16x16x32_bf16(pah, vl, o[nf], 0, 0, 0);
            o[nf] = __builtin_amdgcn_mfma_f32_16x16x32_bf16(pah, vh, o[nf], 0, 0, 0);
        }
    }
    float invl[4];
#pragma unroll
    for (int j = 0; j < 4; ++j) invl[j] = 1.f / ls[j];
#pragma unroll
    for (int nf = 0; nf < 8; ++nf)
#pragma unroll
        for (int j = 0; j < 4; ++j) {
            long idx = (long)(b * SEQ + qbase + 4 * g + j) * DIM + h * HDIM + nf * 16 + lr;
            of[idx] = o[nf][j] * invl[j];
        }
}

// ---------------- router: sigmoid gate + top-4 + renorm ----------------
__global__ __launch_bounds__(256)
void router_k(const float* __restrict__ x, const float* __restrict__ gw,
              float* __restrict__ topw, int* __restrict__ topi,
              int* __restrict__ posb, int* __restrict__ counts)
{
    int t = blockIdx.x, tid = threadIdx.x;
    int e = tid & 31, ch = tid >> 5;
    const float* xp = x + (long)t * DIM + ch * 256;
    float p = 0.f;
    for (int d = 0; d < 256; ++d) p += xp[d] * gw[(ch * 256 + d) * NE + e];
    __shared__ float red[8][32];
    __shared__ float gv[32];
    red[ch][e] = p;
    __syncthreads();
    if (tid < 32) {
        float s = 0.f;
        for (int c = 0; c < 8; ++c) s += red[c][tid];
        gv[tid] = 1.f / (1.f + expf(-s));
    }
    __syncthreads();
    if (tid == 0) {
        float lg[32];
        for (int i = 0; i < 32; ++i) lg[i] = gv[i];
        float tv[TOPK]; int ti[TOPK]; float wsum = 0.f;
        for (int j = 0; j < TOPK; ++j) {
            float bv = -1e30f; int bi = 0;
            for (int i = 0; i < 32; ++i) if (lg[i] > bv) { bv = lg[i]; bi = i; }
            tv[j] = bv; ti[j] = bi; lg[bi] = -1e30f; wsum += bv;
        }
        float r = 1.f / wsum;
        for (int j = 0; j < TOPK; ++j) {
            topw[t * TOPK + j] = tv[j] * r;
            topi[t * TOPK + j] = ti[j];
            posb[t * TOPK + j] = atomicAdd(&counts[ti[j]], 1);
        }
    }
}

__global__ void initmoe_k(int* __restrict__ rowmap, float* __restrict__ wslot, int* __restrict__ counts)
{
    int i = blockIdx.x * 256 + threadIdx.x;
    if (i < MAXROWS) { rowmap[i] = -1; wslot[i] = 0.f; }
    if (i < NE) counts[i] = 0;
}

__global__ void prep_k(const int* __restrict__ counts, int* __restrict__ padoff,
                       int* __restrict__ tile_e, int* __restrict__ tile_base, int* __restrict__ ntl)
{
    if (threadIdx.x == 0 && blockIdx.x == 0) {
        int nt = 0, rb = 0;
        for (int e = 0; e < NE; ++e) {
            padoff[e] = rb;
            int c = counts[e];
            int te = (c + 127) >> 7;
            for (int i = 0; i < te; ++i) { tile_e[nt] = e; tile_base[nt] = rb + i * 128; ++nt; }
            rb += te * 128;
        }
        *ntl = nt;
    }
}

__global__ void scatter_k(const int* __restrict__ topi, const float* __restrict__ topw,
                          const int* __restrict__ posb, const int* __restrict__ padoff,
                          int* __restrict__ rowmap, float* __restrict__ wslot)
{
    int i = blockIdx.x * 256 + threadIdx.x;
    if (i < T_TOK * TOPK) {
        int e = topi[i];
        int s = padoff[e] + posb[i];
        rowmap[s] = i >> 2;
        wslot[s] = topw[i];
    }
}

// ---------------- launch ----------------
extern "C" void kernel_launch(void* const* d_in, const int* in_sizes, int n_in,
                              void* d_out, int out_size, void* d_ws, size_t ws_size,
                              hipStream_t stream)
{
    (void)in_sizes; (void)n_in; (void)out_size; (void)ws_size;
    const int*   positions = (const int*)  d_in[0];
    const float* hidden    = (const float*)d_in[1];
    const float* in_ln     = (const float*)d_in[2];
    const float* post_ln   = (const float*)d_in[3];
    const float* q_norm    = (const float*)d_in[4];
    const float* k_norm    = (const float*)d_in[5];
    const float* wq        = (const float*)d_in[6];
    const float* wk        = (const float*)d_in[7];
    const float* wv        = (const float*)d_in[8];
    const float* wo        = (const float*)d_in[9];
    const float* gate_w    = (const float*)d_in[10];
    const float* sh_wg     = (const float*)d_in[11];
    const float* sh_wu     = (const float*)d_in[12];
    const float* sh_wd     = (const float*)d_in[13];
    const float* e_wg      = (const float*)d_in[14];
    const float* e_wu      = (const float*)d_in[15];
    const float* e_wd      = (const float*)d_in[16];
    float* out = (float*)d_out;
    char* ws = (char*)d_ws;

    // [0,16M): hf -> attnf -> h2lnf (sequential lifetimes)
    // [16M,40M): qf(16-32) kf(32-36) vf(36-40) -> interbf
    float* hf      = (float*)(ws + 0);
    float* attnf   = (float*)(ws + 0);
    float* h2lnf   = (float*)(ws + 0);
    float* qf      = (float*)(ws + 16777216);
    short* interbf = (short*)(ws + 16777216);
    float* kf      = (float*)(ws + 33554432);
    float* vf      = (float*)(ws + 37748736);
    float* h2      = (float*)(ws + 41943040);
    short* h2lnbf  = (short*)(ws + 58720256);
    short* shint   = (short*)(ws + 67108864);
    float* topw    = (float*)(ws + 75497472);
    int*   topi    = (int*)  (ws + 75530240);
    int*   posb    = (int*)  (ws + 75563008);
    int*   counts  = (int*)  (ws + 75595776);
    int*   padoff  = (int*)  (ws + 75596032);
    int*   ntl     = (int*)  (ws + 75596288);
    int*   tile_e  = (int*)  (ws + 75596544);
    int*   tile_b  = (int*)  (ws + 75597056);
    int*   rowmap  = (int*)  (ws + 75597568);
    float* wslot   = (float*)(ws + 75646720);

    dim3 blk(256);

    // 1) input RMSNorm -> fp32
    rmsnorm_k<false,true><<<T_TOK, blk, 0, stream>>>(hidden, in_ln, nullptr, hf);
    // 2) QKV projections (split-precision)
    gemmsp_k<0><<<dim3(16,16), blk, 0, stream>>>(hf, wq, qf, nullptr, 2048, 2048);
    gemmsp_k<0><<<dim3(16,4),  blk, 0, stream>>>(hf, wk, kf, nullptr,  512, 2048);
    gemmsp_k<0><<<dim3(16,4),  blk, 0, stream>>>(hf, wv, vf, nullptr,  512, 2048);
    // 3) qk-norm + rope in place (q scaled by HD^-0.5)
    rope_k<<<dim3(T_TOK,5), blk, 0, stream>>>(qf, kf, q_norm, k_norm, positions);
    // 4) causal flash attention (split-precision)
    attn_k<<<512, blk, 0, stream>>>(qf, kf, vf, attnf);
    // 5) output projection + residual (split-precision)
    gemmsp_k<1><<<dim3(16,16), blk, 0, stream>>>(attnf, wo, h2, hidden, 2048, 2048);
    // 6) post-attn RMSNorm (bf16 for experts + fp32 for router)
    rmsnorm_k<true,true><<<T_TOK, blk, 0, stream>>>(h2, post_ln, h2lnbf, h2lnf);
    // 7) router + MoE bookkeeping
    initmoe_k<<<48, blk, 0, stream>>>(rowmap, wslot, counts);
    router_k<<<T_TOK, blk, 0, stream>>>(h2lnf, gate_w, topw, topi, posb, counts);
    prep_k<<<1, 64, 0, stream>>>(counts, padoff, tile_e, tile_b, ntl);
    scatter_k<<<32, blk, 0, stream>>>(topi, topw, posb, padoff, rowmap, wslot);
    // 8) shared expert SwiGLU (bf16)
    gemm_k<2,false,false,true><<<dim3(16,16), blk, 30720, stream>>>(h2lnbf, sh_wg, sh_wu, nullptr, shint, nullptr, 2048, 2048, nullptr, nullptr, nullptr, nullptr, 0, nullptr);
    gemm_k<1,false,false,false><<<dim3(16,16), blk, 20480, stream>>>(shint, sh_wd, nullptr, out, nullptr, h2, 2048, 2048, nullptr, nullptr, nullptr, nullptr, 0, nullptr);
    // 9) routed experts: gathered SwiGLU then weighted scatter-add (bf16)
    gemm_k<2,true,true,true><<<dim3(MAXTILES,8), blk, 30720, stream>>>(h2lnbf, e_wg, e_wu, nullptr, interbf, nullptr, 1024, 2048, rowmap, tile_e, tile_b, ntl, (long)2048*1024, nullptr);
    gemm_k<4,false,true,false><<<dim3(MAXTILES,16), blk, 20480, stream>>>(interbf, e_wd, nullptr, out, nullptr, nullptr, 2048, 1024, rowmap, tile_e, tile_b, ntl, (long)1024*2048, wslot);
}

// Round 4
// 1299.111 us; speedup vs baseline: 1.9152x; 1.9152x over previous
//
#include <hip/hip_runtime.h>

// Problem constants
#define T_TOK 2048   // B*S
#define DIM   2048
#define NQ    16
#define NKV   4
#define HDIM  128
#define NE    32
#define TOPK  4
#define FF    1024
#define FSH   2048
#define SEQ   1024
#define MAXROWS 12288
#define MAXTILES 96

typedef __attribute__((ext_vector_type(4))) float f32x4;
typedef __attribute__((ext_vector_type(8))) short bf16x8;

__device__ __forceinline__ short f2bf(float f) {
    union { float f; unsigned u; } c; c.f = f;
    unsigned r = (c.u + 0x7fffu + ((c.u >> 16) & 1u)) >> 16;
    return (short)r;
}
__device__ __forceinline__ float bf2f(short h) {
    union { unsigned u; float f; } c; c.u = ((unsigned)(unsigned short)h) << 16;
    return c.f;
}
__device__ __forceinline__ void splitf(float v, short& hi, short& lo) {
    hi = f2bf(v);
    lo = f2bf(v - bf2f(hi));
}
// bijective XCD-chunk swizzle (m204): consecutive virtual ids land on same XCD
__device__ __forceinline__ int xcd_swz(int lin, int total) {
    int q8 = total >> 3, r8 = total & 7;
    int xcd = lin & 7, idx = lin >> 3;
    return (xcd < r8 ? xcd * (q8 + 1) : r8 * (q8 + 1) + (xcd - r8) * q8) + idx;
}

// ---------------- RMSNorm (one block per token, D=2048) ----------------
template<bool WBF, bool WF>
__global__ __launch_bounds__(256)
void rmsnorm_k(const float* __restrict__ x, const float* __restrict__ sc,
               short* __restrict__ ybf, float* __restrict__ yf)
{
    long base = (long)blockIdx.x * DIM;
    int tid = threadIdx.x;
    const float* xp = x + base + tid * 8;
    float4 a = *(const float4*)xp;
    float4 b = *(const float4*)(xp + 4);
    float ss = a.x*a.x + a.y*a.y + a.z*a.z + a.w*a.w
             + b.x*b.x + b.y*b.y + b.z*b.z + b.w*b.w;
#pragma unroll
    for (int off = 32; off > 0; off >>= 1) ss += __shfl_xor(ss, off);
    __shared__ float red[4];
    if ((tid & 63) == 0) red[tid >> 6] = ss;
    __syncthreads();
    float s = red[0] + red[1] + red[2] + red[3];
    float inv = rsqrtf(s * (1.f / DIM) + 1e-6f);
    const float* sp = sc + tid * 8;
    float4 s0 = *(const float4*)sp;
    float4 s1 = *(const float4*)(sp + 4);
    float o[8];
    o[0]=a.x*inv*s0.x; o[1]=a.y*inv*s0.y; o[2]=a.z*inv*s0.z; o[3]=a.w*inv*s0.w;
    o[4]=b.x*inv*s1.x; o[5]=b.y*inv*s1.y; o[6]=b.z*inv*s1.z; o[7]=b.w*inv*s1.w;
    if (WBF) {
        union { short s[8]; int4 v; } pk;
#pragma unroll
        for (int i = 0; i < 8; ++i) pk.s[i] = f2bf(o[i]);
        *(int4*)(ybf + base + tid * 8) = pk.v;
    }
    if (WF) {
        float4 w0; w0.x=o[0]; w0.y=o[1]; w0.z=o[2]; w0.w=o[3];
        float4 w1; w1.x=o[4]; w1.y=o[5]; w1.z=o[6]; w1.w=o[7];
        *(float4*)(yf + base + tid * 8) = w0;
        *(float4*)(yf + base + tid * 8 + 4) = w1;
    }
}

// ------- Split-precision GEMM: C[M,N] = A_f32[M,K] @ B_f32[K,N] (~fp32 acc) -------
// 3-term bf16 split: x = hi + lo; x*y ~= hi*hi + hi*lo + lo*hi  (rel err ~1e-5)
// EPI 0: Cf = acc ; 1: Cf = acc + addb
// Pipelined: K-step t+1 global loads issued before MFMA(t) (T14).
// NOTE: no min-waves launch bound — (256,3) capped VGPR at 84 and spilled (round 3).
template<int EPI>
__global__ __launch_bounds__(256)
void gemmsp_k(const float* __restrict__ A, const float* __restrict__ B,
              float* __restrict__ Cf, const float* __restrict__ addb,
              int N, int K)
{
    int nby = gridDim.y;
    int total = gridDim.x * nby;
    int lin = blockIdx.x + gridDim.x * blockIdx.y;
    int vt = xcd_swz(lin, total);
    int row0 = (vt / nby) * 128, col0 = (vt % nby) * 128;
    __shared__ short Ah[5120], Al[5120], Bh[5120], Bl[5120];
    int tid = threadIdx.x;
    int w = tid >> 6, l = tid & 63, g = l >> 4, lr = l & 15;
    int wr = w >> 1, wc = w & 1;
    f32x4 acc[4][4];
#pragma unroll
    for (int m = 0; m < 4; ++m)
#pragma unroll
        for (int n = 0; n < 4; ++n) acc[m][n] = (f32x4){0,0,0,0};
    int ar = tid >> 1, ak = (tid & 1) * 16;
    int bk0 = (tid >> 5) * 4, bc0 = (tid & 31) * 4;
    const float* apb = A + (long)(row0 + ar) * K + ak;
    const float* bpb = B + (long)bk0 * N + col0 + bc0;
    float4 av[4], bv[4];
#pragma unroll
    for (int q = 0; q < 4; ++q) av[q] = *(const float4*)(apb + q * 4);
#pragma unroll
    for (int q = 0; q < 4; ++q) bv[q] = *(const float4*)(bpb + (long)q * N);
    for (int kk = 0; kk < K; kk += 32) {
        __syncthreads();
        // stage A hi/lo from regs
#pragma unroll
        for (int q = 0; q < 4; ++q) {
            short4 h4, l4;
            splitf(av[q].x, h4.x, l4.x); splitf(av[q].y, h4.y, l4.y);
            splitf(av[q].z, h4.z, l4.z); splitf(av[q].w, h4.w, l4.w);
            *(short4*)(Ah + ar * 40 + ak + q * 4) = h4;
            *(short4*)(Al + ar * 40 + ak + q * 4) = l4;
        }
        // stage B hi/lo transposed 4x4, swizzled 16B blocks
#pragma unroll
        for (int j = 0; j < 4; ++j) {
            short4 h4, l4;
            splitf(((const float*)&bv[0])[j], h4.x, l4.x);
            splitf(((const float*)&bv[1])[j], h4.y, l4.y);
            splitf(((const float*)&bv[2])[j], h4.z, l4.z);
            splitf(((const float*)&bv[3])[j], h4.w, l4.w);
            int c = bc0 + j;
            int blk = (bk0 >> 3) ^ ((c >> 2) & 3);
            *(short4*)(Bh + c * 40 + blk * 8 + (bk0 & 4)) = h4;
            *(short4*)(Bl + c * 40 + blk * 8 + (bk0 & 4)) = l4;
        }
        // prefetch next K-step (in flight across barrier + ds_read + MFMA)
        if (kk + 32 < K) {
            const float* ap = apb + kk + 32;
            const float* bp = bpb + (long)(kk + 32) * N;
#pragma unroll
            for (int q = 0; q < 4; ++q) av[q] = *(const float4*)(ap + q * 4);
#pragma unroll
            for (int q = 0; q < 4; ++q) bv[q] = *(const float4*)(bp + (long)q * N);
        }
        __syncthreads();
        bf16x8 ah[4], al[4], bh[4], bl[4];
#pragma unroll
        for (int m = 0; m < 4; ++m) {
            int off = (wr * 64 + m * 16 + lr) * 40 + g * 8;
            ah[m] = *(const bf16x8*)(Ah + off);
            al[m] = *(const bf16x8*)(Al + off);
        }
#pragma unroll
        for (int n = 0; n < 4; ++n) {
            int c = wc * 64 + n * 16 + lr;
            int blk = g ^ ((c >> 2) & 3);
            bh[n] = *(const bf16x8*)(Bh + c * 40 + blk * 8);
            bl[n] = *(const bf16x8*)(Bl + c * 40 + blk * 8);
        }
#pragma unroll
        for (int m = 0; m < 4; ++m)
#pragma unroll
            for (int n = 0; n < 4; ++n) {
                acc[m][n] = __builtin_amdgcn_mfma_f32_16x16x32_bf16(al[m], bh[n], acc[m][n], 0, 0, 0);
                acc[m][n] = __builtin_amdgcn_mfma_f32_16x16x32_bf16(ah[m], bl[n], acc[m][n], 0, 0, 0);
                acc[m][n] = __builtin_amdgcn_mfma_f32_16x16x32_bf16(ah[m], bh[n], acc[m][n], 0, 0, 0);
            }
    }
#pragma unroll
    for (int m = 0; m < 4; ++m)
#pragma unroll
        for (int n = 0; n < 4; ++n)
#pragma unroll
            for (int j = 0; j < 4; ++j) {
                int row = row0 + wr * 64 + m * 16 + 4 * g + j;
                int col = col0 + wc * 64 + n * 16 + lr;
                float v = acc[m][n][j];
                if (EPI == 0) Cf[(long)row * N + col] = v;
                else Cf[(long)row * N + col] = v + addb[(long)row * N + col];
            }
}

// ---------------- bf16 GEMM (post-router path), pipelined ----------------
// EPI 2: Cbf = bf16(silu(acc0)*acc1) (DUAL) ; 4: atomicAdd(Cf[tok*DIM+col], wslot[row]*acc)
// EPI 1: Cf = acc + addb
template<int EPI, bool GATHER, bool EXPERT, bool DUAL>
__global__ __launch_bounds__(256)
void gemm_k(const short* __restrict__ A, const float* __restrict__ B0g,
            const float* __restrict__ B1g, float* __restrict__ Cf,
            short* __restrict__ Cbf, const float* __restrict__ addb,
            int N, int K,
            const int* __restrict__ rowmap, const int* __restrict__ tile_e,
            const int* __restrict__ tile_base, const int* __restrict__ ntiles,
            long strideB, const float* __restrict__ wslot)
{
    int nby = gridDim.y;
    int total = gridDim.x * nby;
    int lin = blockIdx.x + gridDim.x * blockIdx.y;
    int vt = xcd_swz(lin, total);
    int bx = vt / nby, by = vt % nby;
    int row0;
    const float* B0; const float* B1 = nullptr;
    if (EXPERT) {
        if (bx >= *ntiles) return;
        int e = tile_e[bx];
        row0 = tile_base[bx];
        B0 = B0g + (long)e * strideB;
        if (DUAL) B1 = B1g + (long)e * strideB;
    } else {
        row0 = bx * 128; B0 = B0g; B1 = B1g;
    }
    int col0 = by * 128;
    extern __shared__ short lds[];
    short* As  = lds;          // [128][40]
    short* Bs0 = lds + 5120;   // [128 cols][40 k] swizzled
    short* Bs1 = lds + 10240;
    int tid = threadIdx.x;
    int w = tid >> 6, l = tid & 63, g = l >> 4, lr = l & 15;
    int wr = w >> 1, wc = w & 1;
    f32x4 acc0[4][4]; f32x4 acc1[4][4];
#pragma unroll
    for (int m = 0; m < 4; ++m)
#pragma unroll
        for (int n = 0; n < 4; ++n) {
            acc0[m][n] = (f32x4){0,0,0,0};
            if (DUAL) acc1[m][n] = (f32x4){0,0,0,0};
        }
    int ar = tid >> 2, ak = (tid & 3) * 8;
    int bk0 = (tid >> 5) * 4, bc0 = (tid & 31) * 4;
    // hoist row gather out of K-loop
    bool rok[2]; const short* abase[2];
#pragma unroll
    for (int it = 0; it < 2; ++it) {
        int r = row0 + ar + it * 64;
        int sr = GATHER ? rowmap[r] : r;
        rok[it] = (!GATHER) || (sr >= 0);
        abase[it] = A + (long)(rok[it] ? sr : 0) * K + ak;
    }
    const float* b0b = B0 + (long)bk0 * N + col0 + bc0;
    const float* b1b = DUAL ? (B1 + (long)bk0 * N + col0 + bc0) : nullptr;
    int4 aval[2]; float4 b0v[4], b1v[4];
#pragma unroll
    for (int it = 0; it < 2; ++it)
        aval[it] = rok[it] ? *(const int4*)(abase[it]) : (int4){0,0,0,0};
#pragma unroll
    for (int q = 0; q < 4; ++q) {
        b0v[q] = *(const float4*)(b0b + (long)q * N);
        if (DUAL) b1v[q] = *(const float4*)(b1b + (long)q * N);
    }
    for (int kk = 0; kk < K; kk += 32) {
        __syncthreads();
#pragma unroll
        for (int it = 0; it < 2; ++it)
            *(int4*)(As + (ar + it * 64) * 40 + ak) = aval[it];
#pragma unroll
        for (int j = 0; j < 4; ++j) {
            short4 pk;
            pk.x = f2bf(((const float*)&b0v[0])[j]);
            pk.y = f2bf(((const float*)&b0v[1])[j]);
            pk.z = f2bf(((const float*)&b0v[2])[j]);
            pk.w = f2bf(((const float*)&b0v[3])[j]);
            int c = bc0 + j;
            int blk = (bk0 >> 3) ^ ((c >> 2) & 3);
            *(short4*)(Bs0 + c * 40 + blk * 8 + (bk0 & 4)) = pk;
            if (DUAL) {
                short4 qk;
                qk.x = f2bf(((const float*)&b1v[0])[j]);
                qk.y = f2bf(((const float*)&b1v[1])[j]);
                qk.z = f2bf(((const float*)&b1v[2])[j]);
                qk.w = f2bf(((const float*)&b1v[3])[j]);
                *(short4*)(Bs1 + c * 40 + blk * 8 + (bk0 & 4)) = qk;
            }
        }
        // prefetch next K-step
        if (kk + 32 < K) {
            int ko = kk + 32;
#pragma unroll
            for (int it = 0; it < 2; ++it)
                aval[it] = rok[it] ? *(const int4*)(abase[it] + ko) : (int4){0,0,0,0};
#pragma unroll
            for (int q = 0; q < 4; ++q) {
                b0v[q] = *(const float4*)(b0b + (long)(ko + q) * N);
                if (DUAL) b1v[q] = *(const float4*)(b1b + (long)(ko + q) * N);
            }
        }
        __syncthreads();
        bf16x8 af[4], b0f[4], b1f[4];
#pragma unroll
        for (int m = 0; m < 4; ++m)
            af[m] = *(const bf16x8*)(As + (wr * 64 + m * 16 + lr) * 40 + g * 8);
#pragma unroll
        for (int n = 0; n < 4; ++n) {
            int c = wc * 64 + n * 16 + lr;
            int blk = g ^ ((c >> 2) & 3);
            b0f[n] = *(const bf16x8*)(Bs0 + c * 40 + blk * 8);
            if (DUAL) b1f[n] = *(const bf16x8*)(Bs1 + c * 40 + blk * 8);
        }
#pragma unroll
        for (int m = 0; m < 4; ++m)
#pragma unroll
            for (int n = 0; n < 4; ++n) {
                acc0[m][n] = __builtin_amdgcn_mfma_f32_16x16x32_bf16(af[m], b0f[n], acc0[m][n], 0, 0, 0);
                if (DUAL)
                    acc1[m][n] = __builtin_amdgcn_mfma_f32_16x16x32_bf16(af[m], b1f[n], acc1[m][n], 0, 0, 0);
            }
    }
#pragma unroll
    for (int m = 0; m < 4; ++m)
#pragma unroll
        for (int n = 0; n < 4; ++n)
#pragma unroll
            for (int j = 0; j < 4; ++j) {
                int row = row0 + wr * 64 + m * 16 + 4 * g + j;
                int col = col0 + wc * 64 + n * 16 + lr;
                float v = acc0[m][n][j];
                if (EPI == 1) Cf[(long)row * N + col] = v + addb[(long)row * N + col];
                else if (EPI == 2) {
                    float uu = acc1[m][n][j];
                    float sg = v / (1.f + __expf(-v));
                    Cbf[(long)row * N + col] = f2bf(sg * uu);
                } else if (EPI == 4) {
                    int tok = rowmap[row];
                    if (tok >= 0) atomicAdd(&Cf[(long)tok * DIM + col], wslot[row] * v);
                }
            }
}

// ---------------- qk-norm + neox RoPE + scale, fp32 in-place ----------------
__global__ __launch_bounds__(256)
void rope_k(float* __restrict__ qf, float* __restrict__ kf,
            const float* __restrict__ qn, const float* __restrict__ kn,
            const int* __restrict__ posp)
{
    int t = blockIdx.x;
    int w = threadIdx.x >> 6, l = threadIdx.x & 63;
    int hi = blockIdx.y * 4 + w;   // 0..19
    float* src; const float* nrm; float esc;
    if (hi < NQ) {
        src = qf + (long)t * DIM + hi * HDIM; nrm = qn;
        esc = 0.08838834764831843f;  // HD^-0.5 folded into q
    } else {
        int kh = hi - NQ;
        src = kf + (long)t * (NKV * HDIM) + kh * HDIM; nrm = kn;
        esc = 1.f;
    }
    float x1 = src[l], x2 = src[l + 64];
    float ss = x1 * x1 + x2 * x2;
#pragma unroll
    for (int off = 32; off > 0; off >>= 1) ss += __shfl_xor(ss, off);
    float inv = rsqrtf(ss * (1.f / HDIM) + 1e-6f);
    float a1 = x1 * inv * nrm[l], a2 = x2 * inv * nrm[l + 64];
    float p = (float)posp[t];
    float fr = expf((float)l * -0.21586735246819178f); // -ln(1e6)/64
    float ang = p * fr;
    float cv = cosf(ang), sv = sinf(ang);
    src[l]      = (a1 * cv - a2 * sv) * esc;
    src[l + 64] = (a1 * sv + a2 * cv) * esc;
}

// ---------------- flash attention (causal, GQA) — split-bf16, ~fp32 ----------------
__global__ __launch_bounds__(256)
void attn_k(const float* __restrict__ qf, const float* __restrict__ kf,
            const float* __restrict__ vf, float* __restrict__ of)
{
    int blk = blockIdx.x;
    int qt = blk & 15, bh = blk >> 4;
    int h = bh & (NQ - 1), b = bh >> 4;
    int kvh = h >> 2;
    int tid = threadIdx.x;
    int w = tid >> 6, l = tid & 63, g = l >> 4, lr = l & 15;
    int q0 = qt * 64, qbase = q0 + w * 16;
    const float* qp = qf + ((long)(b * SEQ + qbase + lr) * DIM + h * HDIM);
    bf16x8 qh[4], ql[4];
#pragma unroll
    for (int kc = 0; kc < 4; ++kc) {
        float4 f0 = *(const float4*)(qp + kc * 32 + 8 * g);
        float4 f1 = *(const float4*)(qp + kc * 32 + 8 * g + 4);
        union { short s[8]; bf16x8 v; } uh, ul;
#pragma unroll
        for (int i = 0; i < 4; ++i) {
            splitf(((const float*)&f0)[i], uh.s[i], ul.s[i]);
            splitf(((const float*)&f1)[i], uh.s[4 + i], ul.s[4 + i]);
        }
        qh[kc] = uh.v; ql[kc] = ul.v;
    }
    f32x4 o[8];
#pragma unroll
    for (int i = 0; i < 8; ++i) o[i] = (f32x4){0,0,0,0};
    float mr[4] = {-1e30f, -1e30f, -1e30f, -1e30f};
    float ls[4] = {0, 0, 0, 0};
    __shared__ short Vth[5120], Vtl[5120];      // [hd][40 keys]
    __shared__ short Plh[2560], Pll[2560];      // per-wave [16 q][40 keys]
    int nsteps = 2 * (qt + 1);
    for (int st = 0; st < nsteps; ++st) {
        int kb = st * 32;
        __syncthreads();
        {   // stage V transposed + split: Vt[hd][key]
            int key = tid >> 3, hx = (tid & 7) * 16;
            const float* vp = vf + ((long)(b * SEQ + kb + key) * (NKV * HDIM) + kvh * HDIM + hx);
#pragma unroll
            for (int q = 0; q < 4; ++q) {
                float4 v = *(const float4*)(vp + q * 4);
#pragma unroll
                for (int i = 0; i < 4; ++i) {
                    short hh, ll;
                    splitf(((const float*)&v)[i], hh, ll);
                    Vth[(hx + q * 4 + i) * 40 + key] = hh;
                    Vtl[(hx + q * 4 + i) * 40 + key] = ll;
                }
            }
        }
        __syncthreads();
        f32x4 sa[2]; sa[0] = (f32x4){0,0,0,0}; sa[1] = (f32x4){0,0,0,0};
#pragma unroll
        for (int kc = 0; kc < 4; ++kc)
#pragma unroll
            for (int n = 0; n < 2; ++n) {
                const float* kp = kf + ((long)(b * SEQ + kb + n * 16 + lr) * (NKV * HDIM) + kvh * HDIM + kc * 32 + 8 * g);
                float4 f0 = *(const float4*)kp;
                float4 f1 = *(const float4*)(kp + 4);
                union { short s[8]; bf16x8 v; } uh, ul;
#pragma unroll
                for (int i = 0; i < 4; ++i) {
                    splitf(((const float*)&f0)[i], uh.s[i], ul.s[i]);
                    splitf(((const float*)&f1)[i], uh.s[4 + i], ul.s[4 + i]);
                }
                sa[n] = __builtin_amdgcn_mfma_f32_16x16x32_bf16(ql[kc], uh.v, sa[n], 0, 0, 0);
                sa[n] = __builtin_amdgcn_mfma_f32_16x16x32_bf16(qh[kc], ul.v, sa[n], 0, 0, 0);
                sa[n] = __builtin_amdgcn_mfma_f32_16x16x32_bf16(qh[kc], uh.v, sa[n], 0, 0, 0);
            }
        // causal mask
#pragma unroll
        for (int n = 0; n < 2; ++n)
#pragma unroll
            for (int j = 0; j < 4; ++j) {
                int key = kb + n * 16 + lr;
                int qr = qbase + 4 * g + j;
                if (key > qr) sa[n][j] = -1e30f;
            }
        // online softmax (fp32), P stored as hi/lo bf16 planes
#pragma unroll
        for (int j = 0; j < 4; ++j) {
            float v = fmaxf(sa[0][j], sa[1][j]);
#pragma unroll
            for (int off = 1; off < 16; off <<= 1) v = fmaxf(v, __shfl_xor(v, off));
            float mn = fmaxf(mr[j], v);
            float sc = __expf(mr[j] - mn);
            mr[j] = mn;
            float p0 = __expf(sa[0][j] - mn);
            float p1 = __expf(sa[1][j] - mn);
            float rs = p0 + p1;
#pragma unroll
            for (int off = 1; off < 16; off <<= 1) rs += __shfl_xor(rs, off);
            ls[j] = ls[j] * sc + rs;
            short hh, ll;
            splitf(p0, hh, ll);
            Plh[w * 640 + (4 * g + j) * 40 + lr] = hh;
            Pll[w * 640 + (4 * g + j) * 40 + lr] = ll;
            splitf(p1, hh, ll);
            Plh[w * 640 + (4 * g + j) * 40 + 16 + lr] = hh;
            Pll[w * 640 + (4 * g + j) * 40 + 16 + lr] = ll;
#pragma unroll
            for (int nf = 0; nf < 8; ++nf) o[nf][j] *= sc;
        }
        asm volatile("s_waitcnt lgkmcnt(0)" ::: "memory");
        bf16x8 pah = *(const bf16x8*)(Plh + w * 640 + lr * 40 + 8 * g);
        bf16x8 pal = *(const bf16x8*)(Pll + w * 640 + lr * 40 + 8 * g);
#pragma unroll
        for (int nf = 0; nf < 8; ++nf) {
            bf16x8 vh = *(const bf16x8*)(Vth + (nf * 16 + lr) * 40 + 8 * g);
            bf16x8 vl = *(const bf16x8*)(Vtl + (nf * 16 + lr) * 40 + 8 * g);
            o[nf] = __builtin_amdgcn_mfma_f32_16x16x32_bf16(pal, vh, o[nf], 0, 0, 0);
            o[nf] = __builtin_amdgcn_mfma_f32_16x16x32_bf16(pah, vl, o[nf], 0, 0, 0);
            o[nf] = __builtin_amdgcn_mfma_f32_16x16x32_bf16(pah, vh, o[nf], 0, 0, 0);
        }
    }
    float invl[4];
#pragma unroll
    for (int j = 0; j < 4; ++j) invl[j] = 1.f / ls[j];
#pragma unroll
    for (int nf = 0; nf < 8; ++nf)
#pragma unroll
        for (int j = 0; j < 4; ++j) {
            long idx = (long)(b * SEQ + qbase + 4 * g + j) * DIM + h * HDIM + nf * 16 + lr;
            of[idx] = o[nf][j] * invl[j];
        }
}

// ---------------- router: sigmoid gate + top-4 + renorm ----------------
__global__ __launch_bounds__(256)
void router_k(const float* __restrict__ x, const float* __restrict__ gw,
              float* __restrict__ topw, int* __restrict__ topi,
              int* __restrict__ posb, int* __restrict__ counts)
{
    int t = blockIdx.x, tid = threadIdx.x;
    int e = tid & 31, ch = tid >> 5;
    const float* xp = x + (long)t * DIM + ch * 256;
    float p = 0.f;
    for (int d = 0; d < 256; ++d) p += xp[d] * gw[(ch * 256 + d) * NE + e];
    __shared__ float red[8][32];
    __shared__ float gv[32];
    red[ch][e] = p;
    __syncthreads();
    if (tid < 32) {
        float s = 0.f;
        for (int c = 0; c < 8; ++c) s += red[c][tid];
        gv[tid] = 1.f / (1.f + expf(-s));
    }
    __syncthreads();
    if (tid == 0) {
        float lg[32];
        for (int i = 0; i < 32; ++i) lg[i] = gv[i];
        float tv[TOPK]; int ti[TOPK]; float wsum = 0.f;
        for (int j = 0; j < TOPK; ++j) {
            float bv = -1e30f; int bi = 0;
            for (int i = 0; i < 32; ++i) if (lg[i] > bv) { bv = lg[i]; bi = i; }
            tv[j] = bv; ti[j] = bi; lg[bi] = -1e30f; wsum += bv;
        }
        float r = 1.f / wsum;
        for (int j = 0; j < TOPK; ++j) {
            topw[t * TOPK + j] = tv[j] * r;
            topi[t * TOPK + j] = ti[j];
            posb[t * TOPK + j] = atomicAdd(&counts[ti[j]], 1);
        }
    }
}

__global__ void initmoe_k(int* __restrict__ rowmap, float* __restrict__ wslot, int* __restrict__ counts)
{
    int i = blockIdx.x * 256 + threadIdx.x;
    if (i < MAXROWS) { rowmap[i] = -1; wslot[i] = 0.f; }
    if (i < NE) counts[i] = 0;
}

__global__ void prep_k(const int* __restrict__ counts, int* __restrict__ padoff,
                       int* __restrict__ tile_e, int* __restrict__ tile_base, int* __restrict__ ntl)
{
    if (threadIdx.x == 0 && blockIdx.x == 0) {
        int nt = 0, rb = 0;
        for (int e = 0; e < NE; ++e) {
            padoff[e] = rb;
            int c = counts[e];
            int te = (c + 127) >> 7;
            for (int i = 0; i < te; ++i) { tile_e[nt] = e; tile_base[nt] = rb + i * 128; ++nt; }
            rb += te * 128;
        }
        *ntl = nt;
    }
}

__global__ void scatter_k(const int* __restrict__ topi, const float* __restrict__ topw,
                          const int* __restrict__ posb, const int* __restrict__ padoff,
                          int* __restrict__ rowmap, float* __restrict__ wslot)
{
    int i = blockIdx.x * 256 + threadIdx.x;
    if (i < T_TOK * TOPK) {
        int e = topi[i];
        int s = padoff[e] + posb[i];
        rowmap[s] = i >> 2;
        wslot[s] = topw[i];
    }
}

// ---------------- launch ----------------
extern "C" void kernel_launch(void* const* d_in, const int* in_sizes, int n_in,
                              void* d_out, int out_size, void* d_ws, size_t ws_size,
                              hipStream_t stream)
{
    (void)in_sizes; (void)n_in; (void)out_size; (void)ws_size;
    const int*   positions = (const int*)  d_in[0];
    const float* hidden    = (const float*)d_in[1];
    const float* in_ln     = (const float*)d_in[2];
    const float* post_ln   = (const float*)d_in[3];
    const float* q_norm    = (const float*)d_in[4];
    const float* k_norm    = (const float*)d_in[5];
    const float* wq        = (const float*)d_in[6];
    const float* wk        = (const float*)d_in[7];
    const float* wv        = (const float*)d_in[8];
    const float* wo        = (const float*)d_in[9];
    const float* gate_w    = (const float*)d_in[10];
    const float* sh_wg     = (const float*)d_in[11];
    const float* sh_wu     = (const float*)d_in[12];
    const float* sh_wd     = (const float*)d_in[13];
    const float* e_wg      = (const float*)d_in[14];
    const float* e_wu      = (const float*)d_in[15];
    const float* e_wd      = (const float*)d_in[16];
    float* out = (float*)d_out;
    char* ws = (char*)d_ws;

    // [0,16M): hf -> attnf -> h2lnf (sequential lifetimes)
    // [16M,40M): qf(16-32) kf(32-36) vf(36-40) -> interbf
    float* hf      = (float*)(ws + 0);
    float* attnf   = (float*)(ws + 0);
    float* h2lnf   = (float*)(ws + 0);
    float* qf      = (float*)(ws + 16777216);
    short* interbf = (short*)(ws + 16777216);
    float* kf      = (float*)(ws + 33554432);
    float* vf      = (float*)(ws + 37748736);
    float* h2      = (float*)(ws + 41943040);
    short* h2lnbf  = (short*)(ws + 58720256);
    short* shint   = (short*)(ws + 67108864);
    float* topw    = (float*)(ws + 75497472);
    int*   topi    = (int*)  (ws + 75530240);
    int*   posb    = (int*)  (ws + 75563008);
    int*   counts  = (int*)  (ws + 75595776);
    int*   padoff  = (int*)  (ws + 75596032);
    int*   ntl     = (int*)  (ws + 75596288);
    int*   tile_e  = (int*)  (ws + 75596544);
    int*   tile_b  = (int*)  (ws + 75597056);
    int*   rowmap  = (int*)  (ws + 75597568);
    float* wslot   = (float*)(ws + 75646720);

    dim3 blk(256);

    // 1) input RMSNorm -> fp32
    rmsnorm_k<false,true><<<T_TOK, blk, 0, stream>>>(hidden, in_ln, nullptr, hf);
    // 2) QKV projections (split-precision)
    gemmsp_k<0><<<dim3(16,16), blk, 0, stream>>>(hf, wq, qf, nullptr, 2048, 2048);
    gemmsp_k<0><<<dim3(16,4),  blk, 0, stream>>>(hf, wk, kf, nullptr,  512, 2048);
    gemmsp_k<0><<<dim3(16,4),  blk, 0, stream>>>(hf, wv, vf, nullptr,  512, 2048);
    // 3) qk-norm + rope in place (q scaled by HD^-0.5)
    rope_k<<<dim3(T_TOK,5), blk, 0, stream>>>(qf, kf, q_norm, k_norm, positions);
    // 4) causal flash attention (split-precision)
    attn_k<<<512, blk, 0, stream>>>(qf, kf, vf, attnf);
    // 5) output projection + residual (split-precision)
    gemmsp_k<1><<<dim3(16,16), blk, 0, stream>>>(attnf, wo, h2, hidden, 2048, 2048);
    // 6) post-attn RMSNorm (bf16 for experts + fp32 for router)
    rmsnorm_k<true,true><<<T_TOK, blk, 0, stream>>>(h2, post_ln, h2lnbf, h2lnf);
    // 7) router + MoE bookkeeping
    initmoe_k<<<48, blk, 0, stream>>>(rowmap, wslot, counts);
    router_k<<<T_TOK, blk, 0, stream>>>(h2lnf, gate_w, topw, topi, posb, counts);
    prep_k<<<1, 64, 0, stream>>>(counts, padoff, tile_e, tile_b, ntl);
    scatter_k<<<32, blk, 0, stream>>>(topi, topw, posb, padoff, rowmap, wslot);
    // 8) shared expert SwiGLU (bf16)
    gemm_k<2,false,false,true><<<dim3(16,16), blk, 30720, stream>>>(h2lnbf, sh_wg, sh_wu, nullptr, shint, nullptr, 2048, 2048, nullptr, nullptr, nullptr, nullptr, 0, nullptr);
    gemm_k<1,false,false,false><<<dim3(16,16), blk, 20480, stream>>>(shint, sh_wd, nullptr, out, nullptr, h2, 2048, 2048, nullptr, nullptr, nullptr, nullptr, 0, nullptr);
    // 9) routed experts: gathered SwiGLU then weighted scatter-add (bf16)
    gemm_k<2,true,true,true><<<dim3(MAXTILES,8), blk, 30720, stream>>>(h2lnbf, e_wg, e_wu, nullptr, interbf, nullptr, 1024, 2048, rowmap, tile_e, tile_b, ntl, (long)2048*1024, nullptr);
    gemm_k<4,false,true,false><<<dim3(MAXTILES,16), blk, 20480, stream>>>(interbf, e_wd, nullptr, out, nullptr, nullptr, 2048, 1024, rowmap, tile_e, tile_b, ntl, (long)1024*2048, wslot);
}